// Round 1
// baseline (210.496 us; speedup 1.0000x reference)
//
#include <hip/hip_runtime.h>
#include <stdint.h>

// ---------------------------------------------------------------------------
// VarianceMaximizationCovarianceMinimizationLoss on MI355X
//   features [65536,2,256] fp32, labels [65536] int32 -> scalar fp32 loss
// Pipeline:
//   k_hist    : per-class row counts (each label covers vfac rows)
//   k_offsets : exclusive prefix -> offsets, init scatter cursors
//   k_scatter : counting-sort rows into class-contiguous bf16 array (ws)
//               + fused per-class fp32 column sums
//   k_gram    : per-class Gram S[c] = Xc^T Xc via mfma_f32_16x16x32_bf16
//               (transposed+XOR-swizzled LDS staging, atomicAdd flush)
//   k_loss    : cov = (S - n mu mu^T)/(n-1); diag -> std loss, offdiag -> cov^2
// ---------------------------------------------------------------------------

#define NCLS  8
#define D     256
#define CHUNK 512
#define SEG   256
#define EPSF  1e-4f

typedef __bf16 bf16x8 __attribute__((ext_vector_type(8)));
typedef float  f32x4  __attribute__((ext_vector_type(4)));

__device__ __forceinline__ unsigned short f2bf(float f) {
    unsigned int x = __float_as_uint(f);
    x += 0x7fffu + ((x >> 16) & 1u);      // round-to-nearest-even
    return (unsigned short)(x >> 16);
}

// ---- k1a: histogram of row counts per class -------------------------------
__global__ void k_hist(const int* __restrict__ labels, int nlab, int vfac,
                       int* __restrict__ counts) {
    __shared__ int lc[NCLS];
    int t = threadIdx.x;
    if (t < NCLS) lc[t] = 0;
    __syncthreads();
    for (int i = blockIdx.x * blockDim.x + t; i < nlab; i += gridDim.x * blockDim.x)
        atomicAdd(&lc[labels[i] & 7], vfac);
    __syncthreads();
    if (t < NCLS && lc[t]) atomicAdd(&counts[t], lc[t]);
}

// ---- k1b: offsets + cursors ----------------------------------------------
__global__ void k_offsets(const int* __restrict__ counts,
                          int* __restrict__ offsets, int* __restrict__ cursor) {
    if (threadIdx.x == 0) {
        int acc = 0;
        for (int c = 0; c < NCLS; ++c) { offsets[c] = acc; cursor[c] = acc; acc += counts[c]; }
    }
}

// ---- k2: scatter rows into class-sorted bf16 + column sums ----------------
__global__ __launch_bounds__(256) void k_scatter(
    const float* __restrict__ X, const int* __restrict__ labels,
    int nrows, int vfac,
    unsigned short* __restrict__ sorted, int* __restrict__ cursor,
    float* __restrict__ gsums)
{
    __shared__ float sumbuf[4][NCLS][D];         // 32 KB, per-wave class sums
    __shared__ int lcnt[NCLS], lbase[NCLS];
    __shared__ short lrank[SEG];
    __shared__ unsigned char lcls[SEG];

    int t  = threadIdx.x;
    int r0 = blockIdx.x * SEG;

    for (int i = t; i < 4 * NCLS * D; i += 256) ((float*)sumbuf)[i] = 0.f;
    if (t < NCLS) lcnt[t] = 0;
    __syncthreads();

    // phase 1: class + in-block rank per row
    {
        int row = r0 + t;
        if (t < SEG && row < nrows) {
            int c = labels[row / vfac] & 7;
            lcls[t] = (unsigned char)c;
            lrank[t] = (short)atomicAdd(&lcnt[c], 1);
        }
    }
    __syncthreads();
    // phase 2: one global cursor reservation per class per block
    if (t < NCLS) lbase[t] = lcnt[t] ? atomicAdd(&cursor[t], lcnt[t]) : 0;
    __syncthreads();

    // phase 3: wave-per-row copy fp32 -> bf16 + sum accumulation
    int w = t >> 6, lane = t & 63;
    for (int i = w; i < SEG; i += 4) {
        int row = r0 + i;
        if (row >= nrows) break;
        int c = lcls[i];
        int dest = lbase[c] + lrank[i];
        float4 v = *(const float4*)(X + (size_t)row * D + lane * 4);
        float* sb = &sumbuf[w][c][lane * 4];
        sb[0] += v.x; sb[1] += v.y; sb[2] += v.z; sb[3] += v.w;
        ushort4 o;
        o.x = f2bf(v.x); o.y = f2bf(v.y); o.z = f2bf(v.z); o.w = f2bf(v.w);
        *(ushort4*)(sorted + (size_t)dest * D + lane * 4) = o;
    }
    __syncthreads();

    for (int i = t; i < NCLS * D; i += 256) {
        float s = sumbuf[0][0][i] + sumbuf[1][0][i] + sumbuf[2][0][i] + sumbuf[3][0][i];
        atomicAdd(&gsums[i], s);
    }
}

// ---- k3: per-class Gram via MFMA ------------------------------------------
// WG = 512 threads (8 waves, 2x4 -> 128x64 per wave), full 256x256 acc in regs.
// LDS: 64x256 bf16 K-tile stored transposed: element (c,k) at byte
//      c*128 + ((k*2) ^ ((c&7)<<4))   (XOR swizzle -> conflict-free b128 reads)
__global__ __launch_bounds__(512, 2) void k_gram(
    const unsigned short* __restrict__ sorted,
    const int* __restrict__ counts, const int* __restrict__ offsets,
    float* __restrict__ S)
{
    __shared__ __align__(16) unsigned char lds[64 * 256 * 2];   // 32 KB

    int t = threadIdx.x;
    int lane = t & 63;
    int w = t >> 6;
    int wrow = w >> 2, wcol = w & 3;

    // staging coords: 16 k-blocks of 4 rows x 32 col-blocks of 8 cols
    int kblk = t & 15;
    int cblk = t >> 4;

    // work-item table
    int nch[NCLS], ofch[NCLS];
    int T = 0;
    for (int c = 0; c < NCLS; ++c) {
        int n = counts[c];
        nch[c] = (n + CHUNK - 1) / CHUNK;
        ofch[c] = T;
        T += nch[c];
    }

    for (int item = blockIdx.x; item < T; item += gridDim.x) {
        int c = 0;
        while (c < NCLS - 1 && item >= ofch[c + 1]) ++c;
        int chunk = item - ofch[c];
        int base = offsets[c] + chunk * CHUNK;
        int rows = min(CHUNK, counts[c] - chunk * CHUNK);

        f32x4 acc[8][4];
        #pragma unroll
        for (int i = 0; i < 8; ++i)
            #pragma unroll
            for (int j = 0; j < 4; ++j)
                #pragma unroll
                for (int r = 0; r < 4; ++r) acc[i][j][r] = 0.f;

        int ntiles = (rows + 63) >> 6;
        for (int kt = 0; kt < ntiles; ++kt) {
            // global -> reg (issued before barrier: latency hides under drain)
            uint4 R[4];
            int rbase = kt * 64 + kblk * 4;
            #pragma unroll
            for (int j = 0; j < 4; ++j) {
                int r = rbase + j;
                if (r < rows)
                    R[j] = *(const uint4*)(sorted + (((size_t)(base + r)) << 8) + cblk * 8);
                else
                    R[j] = make_uint4(0u, 0u, 0u, 0u);
            }
            __syncthreads();   // all waves done reading previous tile
            // reg -> LDS transposed (4 rows packed per b64 write)
            #pragma unroll
            for (int cc = 0; cc < 8; ++cc) {
                int wd = cc >> 1;
                int sh = (cc & 1) * 16;
                unsigned int e0 = ((((const unsigned int*)&R[0])[wd]) >> sh) & 0xffffu;
                unsigned int e1 = ((((const unsigned int*)&R[1])[wd]) >> sh) & 0xffffu;
                unsigned int e2 = ((((const unsigned int*)&R[2])[wd]) >> sh) & 0xffffu;
                unsigned int e3 = ((((const unsigned int*)&R[3])[wd]) >> sh) & 0xffffu;
                int ccol = cblk * 8 + cc;
                int byt = ccol * 128 + ((kblk * 8) ^ (cc << 4));
                *(uint2*)(lds + byt) = make_uint2(e0 | (e1 << 16), e2 | (e3 << 16));
            }
            __syncthreads();
            // compute: 2 k-steps of 32, 12 ds_read_b128 + 32 MFMA per step/wave
            #pragma unroll
            for (int ks = 0; ks < 2; ++ks) {
                int kb2 = ks * 64 + ((lane >> 4) << 4);   // byte offset of k0 in row
                int swz = (lane & 7) << 4;
                bf16x8 af[8], bfr[4];
                #pragma unroll
                for (int ti = 0; ti < 8; ++ti) {
                    int ccol = wrow * 128 + ti * 16 + (lane & 15);
                    af[ti] = __builtin_bit_cast(bf16x8,
                        *(const uint4*)(lds + ccol * 128 + (kb2 ^ swz)));
                }
                #pragma unroll
                for (int tj = 0; tj < 4; ++tj) {
                    int ccol = wcol * 64 + tj * 16 + (lane & 15);
                    bfr[tj] = __builtin_bit_cast(bf16x8,
                        *(const uint4*)(lds + ccol * 128 + (kb2 ^ swz)));
                }
                #pragma unroll
                for (int ti = 0; ti < 8; ++ti)
                    #pragma unroll
                    for (int tj = 0; tj < 4; ++tj)
                        acc[ti][tj] = __builtin_amdgcn_mfma_f32_16x16x32_bf16(
                            af[ti], bfr[tj], acc[ti][tj], 0, 0, 0);
            }
        }

        // flush partial Gram (C/D layout: col = lane&15, row = (lane>>4)*4 + r)
        float* Sc = S + (((size_t)c) << 16);
        #pragma unroll
        for (int ti = 0; ti < 8; ++ti) {
            int row0 = wrow * 128 + ti * 16 + ((lane >> 4) << 2);
            #pragma unroll
            for (int tj = 0; tj < 4; ++tj) {
                int col = wcol * 64 + tj * 16 + (lane & 15);
                #pragma unroll
                for (int r = 0; r < 4; ++r)
                    atomicAdd(&Sc[(row0 + r) * D + col], acc[ti][tj][r]);
            }
        }
        // next item's pre-write barrier orders LDS reuse; no barrier needed here
    }
}

// ---- k4: loss epilogue -----------------------------------------------------
__global__ __launch_bounds__(256) void k_loss(
    const float* __restrict__ S, const float* __restrict__ gsums,
    const int* __restrict__ counts, float* __restrict__ out)
{
    __shared__ float red[256];
    int t = threadIdx.x;
    float local = 0.f;
    const int total = NCLS * D * D;
    for (int idx = blockIdx.x * blockDim.x + t; idx < total; idx += gridDim.x * blockDim.x) {
        int c = idx >> 16;
        int ij = idx & 0xffff;
        int i = ij >> 8, j = ij & 255;
        float n  = (float)counts[c];
        float mi = gsums[c * D + i] / n;
        float mj = gsums[c * D + j] / n;
        float cov = (S[idx] - n * mi * mj) / (n - 1.f);
        float contrib;
        if (i == j) {
            float sd = sqrtf(cov + EPSF);
            contrib = fmaxf(1.f - sd, 0.f) * (1.f / (float)D);
        } else {
            contrib = cov * cov * (1.f / (float)D);
        }
        local += contrib;
    }
    red[t] = local;
    __syncthreads();
    for (int s = 128; s > 0; s >>= 1) {
        if (t < s) red[t] += red[t + s];
        __syncthreads();
    }
    if (t == 0) atomicAdd(out, red[0]);
}

// ---------------------------------------------------------------------------
extern "C" void kernel_launch(void* const* d_in, const int* in_sizes, int n_in,
                              void* d_out, int out_size, void* d_ws, size_t ws_size,
                              hipStream_t stream)
{
    const float* X      = (const float*)d_in[0];
    const int*   labels = (const int*)d_in[1];
    int nfeat = in_sizes[0];
    int nlab  = in_sizes[1];
    int nrows = nfeat / D;            // 131072
    int vfac  = nrows / nlab;         // 2 views per sample

    char* ws = (char*)d_ws;
    size_t sz_sorted = (size_t)nrows * D * 2;            // 67.1 MB bf16
    size_t off_S     = sz_sorted;
    size_t sz_S      = (size_t)NCLS * D * D * 4;         // 2 MB
    size_t off_sums  = off_S + sz_S;
    size_t sz_sums   = (size_t)NCLS * D * 4;             // 8 KB
    size_t off_cnt   = off_sums + sz_sums;
    size_t off_ofs   = off_cnt + 64;
    size_t off_cur   = off_ofs + 64;

    unsigned short* sorted  = (unsigned short*)(ws);
    float*          S       = (float*)(ws + off_S);
    float*          gsums   = (float*)(ws + off_sums);
    int*            counts  = (int*)(ws + off_cnt);
    int*            offsets = (int*)(ws + off_ofs);
    int*            cursor  = (int*)(ws + off_cur);

    hipMemsetAsync(S, 0, sz_S, stream);
    hipMemsetAsync(gsums, 0, sz_sums, stream);
    hipMemsetAsync(counts, 0, 64, stream);
    hipMemsetAsync(d_out, 0, (size_t)out_size * sizeof(float), stream);

    k_hist<<<64, 256, 0, stream>>>(labels, nlab, vfac, counts);
    k_offsets<<<1, 64, 0, stream>>>(counts, offsets, cursor);
    k_scatter<<<(nrows + SEG - 1) / SEG, 256, 0, stream>>>(
        X, labels, nrows, vfac, sorted, cursor, gsums);
    k_gram<<<256, 512, 0, stream>>>(sorted, counts, offsets, S);
    k_loss<<<512, 256, 0, stream>>>(S, gsums, counts, (float*)d_out);
}